// Round 17
// baseline (38.799 us; speedup 1.0000x reference)
//
#include <hip/hip_runtime.h>
#include <math.h>

#define IMG_H 512
#define IMG_W 512
#define PLANE (IMG_H * IMG_W)
#define NB 9
#define LSTR 72    // [0..2]pad [3]=Lhalo [4..67]=cols 0..63 [68]=Rhalo [69..71]pad

typedef __attribute__((ext_vector_type(2))) float f32x2;

__device__ __forceinline__ f32x2 fma2(f32x2 a, f32x2 b, f32x2 c) {
    return __builtin_elementwise_fma(a, b, c);
}
__device__ __forceinline__ f32x2 splat2(float v) { return (f32x2){v, v}; }

// Markstein constant-division: bit-identical to IEEE s/3.0f per lane.
__device__ __forceinline__ f32x2 div3x2(f32x2 s) {
    const f32x2 y0 = splat2(0.33333334f);       // RN(1/3)
    const f32x2 q  = s * y0;
    const f32x2 r  = fma2(splat2(-3.0f), q, s); // exact residual
    return fma2(r, y0, q);
}
__device__ __forceinline__ float div3(float s) {
    const float y0 = 0.33333334f;
    const float q  = s * y0;
    const float r  = fmaf(-3.0f, q, s);
    return fmaf(r, y0, q);
}

// SINGLE-WAVE WORKGROUP kernel: block = 64 threads = 1 wave, owns an
// 8-row x 64-col tile. __syncthreads in a 1-wave block is just an lgkmcnt
// drain (no cross-wave rendezvous) -> kills the barrier convoy that
// phase-locks staging across resident blocks. Per-thread code identical
// to round 15 (best: 32.9 us).
//
// CORRECTNESS MODEL (do not change): decision chain bit-exact vs the fp32 ref:
//   gray  = ((c0+c1)+c2)/3.0f   (== div3, Markstein; packed == scalar per lane)
//   gx,gy = Sobel, tap-lex order, +-1/+-2 exact multiplies  [ORDER FROZEN]
//   fast classifier (err < 6e-5 pb-units); within 1.2e-4 of integer pb
//   (incl. 0/NaN/up==9 edges via d=up-rint(up)) fall back to exact INLINED
//   (float)atan2(fp64) -> /(float)pi*9 -> floored mod 9.
//   up = (sign(gx)^sign(gy)) ? 9-v : v ; L=(int)up (trunc==floor on fast path).
__global__ __launch_bounds__(64, 4) void hog_kernel(const float* __restrict__ x,
                                                    float* __restrict__ out) {
    __shared__ float sgray[10 * LSTR];   // 2880 B
    __shared__ float sbins[64 * NB];     // 2304 B  (5184 B total)

    const int t    = threadIdx.x;
    const int n    = blockIdx.x >> 9;           // 512 blocks per image
    const int rem  = blockIdx.x & 511;
    const int cy   = rem >> 3;
    const int grp  = rem & 7;                   // 8 col-groups of 64
    const int h0   = cy * 8;
    const int wstart = grp * 64;
    const float* xn = x + (size_t)n * 3 * PLANE;

    // halo cols (threads 0..19): row r, left->LDS idx 3, right->idx 68
    if (t < 20) {
        const int r    = t >> 1;
        const int side = t & 1;
        const int h    = h0 - 1 + r;
        const int col  = wstart - 1 + side * 65;
        float g = 0.0f;
        if ((unsigned)h < IMG_H && (unsigned)col < IMG_W) {
            const float* p = xn + (size_t)h * IMG_W + col;
            g = div3((p[0] + p[PLANE]) + p[2 * PLANE]);
        }
        sgray[r * LSTR + 3 + side * 65] = g;
    }
    // interior: 10 rows x 16 float4, packed gray math, aligned ds_write_b128
#pragma unroll
    for (int k = 0; k < 3; k++) {
        const int i4 = t + k * 64;
        if (i4 < 160) {
            const int r  = i4 >> 4;
            const int c4 = i4 & 15;
            const int h  = h0 - 1 + r;
            float4 gv = make_float4(0.0f, 0.0f, 0.0f, 0.0f);
            if ((unsigned)h < IMG_H) {
                const float* p = xn + (size_t)h * IMG_W + wstart + 4 * c4;
                const float4 a = *(const float4*)(p);
                const float4 b = *(const float4*)(p + PLANE);
                const float4 c = *(const float4*)(p + 2 * PLANE);
                const f32x2* a2 = (const f32x2*)&a;
                const f32x2* b2 = (const f32x2*)&b;
                const f32x2* c2 = (const f32x2*)&c;
                const f32x2 g0 = div3x2((a2[0] + b2[0]) + c2[0]);
                const f32x2 g1 = div3x2((a2[1] + b2[1]) + c2[1]);
                gv = make_float4(g0.x, g0.y, g1.x, g1.y);
            }
            *(float4*)&sgray[r * LSTR + 4 + 4 * c4] = gv;
        }
    }
    __syncthreads();   // 1-wave block: lgkmcnt drain only

// Packed dual-pixel classify: windows WA,WB,WC are f32x2 (x=chain A, y=chain B).
#define PIXEL2(WA, WB, WC, LA, LB, W0A, W1A, W0B, W1B)                           \
    {                                                                            \
        const f32x2 tl = WA[0], tcv = WA[1], tr = WA[2];                         \
        const f32x2 ml = WB[0],               mr = WB[2];                        \
        const f32x2 bl = WC[0], bcv = WC[1], br = WC[2];                         \
        const f32x2 gx = ((((tl - tr) + 2.0f * ml) - 2.0f * mr) + bl) - br;      \
        const f32x2 gy = ((((tl + 2.0f * tcv) + tr) - bl) - 2.0f * bcv) - br;    \
        const f32x2 s2v = fma2(gx, gx, gy * gy);                                 \
        float nA, nB;                                                            \
        { float sa = s2v.x, sb = s2v.y;                                          \
          asm("v_sqrt_f32 %0, %1" : "=v"(nA) : "v"(sa));                         \
          asm("v_sqrt_f32 %0, %1" : "=v"(nB) : "v"(sb)); }                       \
        const float faA = fabsf(gx.x), fbA = fabsf(gy.x);                        \
        const float faB = fabsf(gx.y), fbB = fabsf(gy.y);                        \
        const float mnA = fminf(faA, fbA), mxA = fmaxf(faA, fbA);                \
        const float mnB = fminf(faB, fbB), mxB = fmaxf(faB, fbB);                \
        float rA, rB;                                                            \
        asm("v_rcp_f32 %0, %1" : "=v"(rA) : "v"(mxA));                           \
        asm("v_rcp_f32 %0, %1" : "=v"(rB) : "v"(mxB));                           \
        const f32x2 tt = (f32x2){mnA, mnB} * (f32x2){rA, rB};                    \
        const f32x2 ssv = tt * tt;                                               \
        f32x2 po = fma2(ssv, splat2(-0.03357890f), splat2(0.15084052f));         \
        po = fma2(ssv, po, splat2(-0.33355581f));                                \
        po = fma2(ssv, po, splat2(0.55446223f));                                 \
        po = fma2(ssv, po, splat2(-0.95289958f));                                \
        po = fma2(ssv, po, splat2(2.86472384f));   /* pre-scaled by 9/pi */      \
        const f32x2 w   = tt * po;                                               \
        const f32x2 w45 = splat2(4.5f) - w;                                      \
        const float vA = (faA > fbA) ? w45.x : w.x;                              \
        const float vB = (faB > fbB) ? w45.y : w.y;                              \
        const f32x2 vv = (f32x2){vA, vB};                                        \
        const f32x2 v9 = splat2(9.0f) - vv;                                      \
        const int sxA = (int)(__float_as_uint(gx.x) ^ __float_as_uint(gy.x));    \
        const int sxB = (int)(__float_as_uint(gx.y) ^ __float_as_uint(gy.y));    \
        const float upA = (sxA < 0) ? v9.x : vA;                                 \
        const float upB = (sxB < 0) ? v9.y : vB;                                 \
        const f32x2 up2 = (f32x2){upA, upB};                                     \
        const f32x2 rn2 = (f32x2){__builtin_rintf(upA), __builtin_rintf(upB)};   \
        const f32x2 d2  = up2 - rn2;                                             \
        if (fabsf(d2.x) > 1.2e-4f) {            /* NaN -> false -> slow */       \
            LA = (int)upA; W0A = nA; W1A = 1.0f - nA;                            \
        } else {                                                                 \
            const float ph  = (float)atan2((double)gx.x, (double)gy.x);          \
            const float pbf = ph / (float)M_PI * 9.0f;                           \
            int lo = (int)floorf(pbf) % NB; if (lo < 0) lo += NB;                \
            int hi = (int)ceilf(pbf)  % NB; if (hi < 0) hi += NB;                \
            LA = lo;                                                             \
            if (lo == hi) { W0A = nA + (1.0f - nA); W1A = 0.0f; }                \
            else          { W0A = nA; W1A = 1.0f - nA; }                         \
        }                                                                        \
        if (fabsf(d2.y) > 1.2e-4f) {                                             \
            LB = (int)upB; W0B = nB; W1B = 1.0f - nB;                            \
        } else {                                                                 \
            const float ph  = (float)atan2((double)gx.y, (double)gy.y);          \
            const float pbf = ph / (float)M_PI * 9.0f;                           \
            int lo = (int)floorf(pbf) % NB; if (lo < 0) lo += NB;                \
            int hi = (int)ceilf(pbf)  % NB; if (hi < 0) hi += NB;                \
            LB = lo;                                                             \
            if (lo == hi) { W0B = nB + (1.0f - nB); W1B = 0.0f; }                \
            else          { W0B = nB; W1B = 1.0f - nB; }                         \
        }                                                                        \
    }

    f32x2 bins2[NB];
#pragma unroll
    for (int b = 0; b < NB; b++) bins2[b] = splat2(0.0f);

    // packed rolling windows: .x = chain A (rows 0..3), .y = chain B (rows 4..7)
    f32x2 wa[3], wb[3], wc[3];
    {
        const float* p0 = &sgray[0 * LSTR + t];
        const float* p1 = &sgray[1 * LSTR + t];
        const float* p4 = &sgray[4 * LSTR + t];
        const float* p5 = &sgray[5 * LSTR + t];
#pragma unroll
        for (int i = 0; i < 3; i++) {
            wa[i] = (f32x2){p0[3 + i], p4[3 + i]};
            wb[i] = (f32x2){p1[3 + i], p5[3 + i]};
        }
    }

#pragma unroll
    for (int k = 0; k < 4; k++) {
        const float* pA = &sgray[(k + 2) * LSTR + t];
        const float* pB = &sgray[(k + 6) * LSTR + t];
#pragma unroll
        for (int i = 0; i < 3; i++) wc[i] = (f32x2){pA[3 + i], pB[3 + i]};

        int LA, LB; float W0A, W1A, W0B, W1B;
        PIXEL2(wa, wb, wc, LA, LB, W0A, W1A, W0B, W1B)

        const f32x2 w0 = (f32x2){W0A, W0B};
        const f32x2 w1 = (f32x2){W1A, W1B};
        f32x2 sel[NB];
#pragma unroll
        for (int b = 0; b < NB; b++)
            sel[b] = (f32x2){(LA == b) ? 1.0f : 0.0f, (LB == b) ? 1.0f : 0.0f};
#pragma unroll
        for (int b = 0; b < NB; b++)
            bins2[b] = fma2(sel[b], w0, bins2[b]);           // v_pk_fma_f32
#pragma unroll
        for (int b = 0; b < NB; b++)
            bins2[b] = fma2(sel[(b + 8) % 9], w1, bins2[b]); // W1 at L+1 mod 9

#pragma unroll
        for (int q = 0; q < 3; q++) { wa[q] = wb[q]; wb[q] = wc[q]; }
    }
#undef PIXEL2

    float* mybins = &sbins[t * NB];
#pragma unroll
    for (int b = 0; b < NB; b++) mybins[b] = bins2[b].x + bins2[b].y;
    __syncthreads();   // 1-wave block: lgkmcnt drain only

    // cell cc (local cols 8cc..8cc+7) gathers threads 8cc..8cc+7; fixed order
    for (int idx = t; idx < NB * 8; idx += 64) {
        const int b  = idx >> 3;
        const int cc = idx & 7;
        const int base = 8 * cc * NB + b;
        float s = sbins[base];
#pragma unroll
        for (int j = 1; j < 8; j++) s += sbins[base + j * NB];
        out[((size_t)n * NB + b) * 4096 + (size_t)cy * 64 + grp * 8 + cc]
            = s * (1.0f / 64.0f);
    }
}

extern "C" void kernel_launch(void* const* d_in, const int* in_sizes, int n_in,
                              void* d_out, int out_size, void* d_ws, size_t ws_size,
                              hipStream_t stream) {
    const float* x = (const float*)d_in[0];
    float* out = (float*)d_out;
    // 32 images x 64 bands x 8 col-groups = 16384 single-wave blocks
    hog_kernel<<<16384, 64, 0, stream>>>(x, out);
}

// Round 18
// 29.369 us; speedup vs baseline: 1.3211x; 1.3211x over previous
//
#include <hip/hip_runtime.h>
#include <math.h>

#define IMG_H 512
#define IMG_W 512
#define PLANE (IMG_H * IMG_W)
#define NB 9
#define LSTR 136   // [0..2]pad [3]=Lhalo [4..131]=cols 0..127 [132]=Rhalo [133..135]pad

typedef __attribute__((ext_vector_type(2))) float f32x2;

__device__ __forceinline__ f32x2 fma2(f32x2 a, f32x2 b, f32x2 c) {
    return __builtin_elementwise_fma(a, b, c);
}
__device__ __forceinline__ f32x2 splat2(float v) { return (f32x2){v, v}; }

// Markstein constant-division: bit-identical to IEEE s/3.0f per lane.
__device__ __forceinline__ f32x2 div3x2(f32x2 s) {
    const f32x2 y0 = splat2(0.33333334f);       // RN(1/3)
    const f32x2 q  = s * y0;
    const f32x2 r  = fma2(splat2(-3.0f), q, s); // exact residual
    return fma2(r, y0, q);
}
__device__ __forceinline__ float div3(float s) {
    const float y0 = 0.33333334f;
    const float q  = s * y0;
    const float r  = fmaf(-3.0f, q, s);
    return fmaf(r, y0, q);
}

// 16-row x 128-col tile per block (vs r15's 8x256): staging overhead drops
// 10/8 -> 18/16 (-9% loads + gray divs), same 2048 px and 256 threads per
// block. Thread t = col (t&127) x row-half (t>>7); per-thread pixel code is
// IDENTICAL to round 15 (champion, 32.9us). XCD-aware bijective swizzle
// (4096 = 8 XCD x 512) keeps each 3MB image L2-resident on one XCD.
//
// CORRECTNESS MODEL (do not change): decision chain bit-exact vs the fp32 ref:
//   gray  = ((c0+c1)+c2)/3.0f   (== div3, Markstein; packed == scalar per lane)
//   gx,gy = Sobel, tap-lex order, +-1/+-2 exact multiplies  [ORDER FROZEN]
//   fast classifier (err < 6e-5 pb-units); within 1.2e-4 of integer pb
//   (incl. 0/NaN/up==9 edges via d=up-rint(up)) fall back to exact INLINED
//   (float)atan2(fp64) -> /(float)pi*9 -> floored mod 9.
//   up = (sign(gx)^sign(gy)) ? 9-v : v ; L=(int)up (trunc==floor on fast path).
__global__ __launch_bounds__(256, 4) void hog_kernel(const float* __restrict__ x,
                                                     float* __restrict__ out) {
    __shared__ float sgray[18 * LSTR];   //  9792 B
    __shared__ float sbins[256 * NB];    //  9216 B (19008 B total)

    const int t  = threadIdx.x;
    // XCD-aware bijective swizzle: XCD k (= bid%8 under round-robin dispatch)
    // gets virtual blocks k*512..k*512+511 = images 4k..4k+3 entirely.
    const int vb   = (blockIdx.x & 7) * 512 + (blockIdx.x >> 3);
    const int n    = vb >> 7;                   // 128 blocks per image
    const int rem  = vb & 127;
    const int band = rem >> 2;                  // 16-row band, 0..31
    const int grp  = rem & 3;                   // col group of 128, 0..3
    const int th0  = band * 16;
    const int wstart = grp * 128;
    const float* xn = x + (size_t)n * 3 * PLANE;

    const int c  = t & 127;                     // local col
    const int rh = t >> 7;                      // row-half 0/1
    const int rbase = rh * 8;                   // LDS row base for this thread

    // halo cols (threads 0..35): row r (0..17), left->idx 3, right->idx 132
    if (t < 36) {
        const int r    = t >> 1;
        const int side = t & 1;
        const int h    = th0 - 1 + r;
        const int col  = wstart - 1 + side * 129;
        float g = 0.0f;
        if ((unsigned)h < IMG_H && (unsigned)col < IMG_W) {
            const float* p = xn + (size_t)h * IMG_W + col;
            g = div3((p[0] + p[PLANE]) + p[2 * PLANE]);
        }
        sgray[r * LSTR + 3 + side * 129] = g;
    }
    // interior: 18 rows x 32 float4 = 576, packed gray, aligned ds_write_b128
#pragma unroll
    for (int k = 0; k < 3; k++) {
        const int i4 = t + k * 256;
        if (i4 < 576) {
            const int r  = i4 >> 5;
            const int c4 = i4 & 31;
            const int h  = th0 - 1 + r;
            float4 gv = make_float4(0.0f, 0.0f, 0.0f, 0.0f);
            if ((unsigned)h < IMG_H) {
                const float* p = xn + (size_t)h * IMG_W + wstart + 4 * c4;
                const float4 a = *(const float4*)(p);
                const float4 b = *(const float4*)(p + PLANE);
                const float4 cc = *(const float4*)(p + 2 * PLANE);
                const f32x2* a2 = (const f32x2*)&a;
                const f32x2* b2 = (const f32x2*)&b;
                const f32x2* c2 = (const f32x2*)&cc;
                const f32x2 g0 = div3x2((a2[0] + b2[0]) + c2[0]);
                const f32x2 g1 = div3x2((a2[1] + b2[1]) + c2[1]);
                gv = make_float4(g0.x, g0.y, g1.x, g1.y);
            }
            *(float4*)&sgray[r * LSTR + 4 + 4 * c4] = gv;
        }
    }
    __syncthreads();

// Packed dual-pixel classify (identical to r15): WA,WB,WC f32x2 windows.
#define PIXEL2(WA, WB, WC, LA, LB, W0A, W1A, W0B, W1B)                           \
    {                                                                            \
        const f32x2 tl = WA[0], tcv = WA[1], tr = WA[2];                         \
        const f32x2 ml = WB[0],               mr = WB[2];                        \
        const f32x2 bl = WC[0], bcv = WC[1], br = WC[2];                         \
        const f32x2 gx = ((((tl - tr) + 2.0f * ml) - 2.0f * mr) + bl) - br;      \
        const f32x2 gy = ((((tl + 2.0f * tcv) + tr) - bl) - 2.0f * bcv) - br;    \
        const f32x2 s2v = fma2(gx, gx, gy * gy);                                 \
        float nA, nB;                                                            \
        { float sa = s2v.x, sb = s2v.y;                                          \
          asm("v_sqrt_f32 %0, %1" : "=v"(nA) : "v"(sa));                         \
          asm("v_sqrt_f32 %0, %1" : "=v"(nB) : "v"(sb)); }                       \
        const float faA = fabsf(gx.x), fbA = fabsf(gy.x);                        \
        const float faB = fabsf(gx.y), fbB = fabsf(gy.y);                        \
        const float mnA = fminf(faA, fbA), mxA = fmaxf(faA, fbA);                \
        const float mnB = fminf(faB, fbB), mxB = fmaxf(faB, fbB);                \
        float rA, rB;                                                            \
        asm("v_rcp_f32 %0, %1" : "=v"(rA) : "v"(mxA));                           \
        asm("v_rcp_f32 %0, %1" : "=v"(rB) : "v"(mxB));                           \
        const f32x2 tt = (f32x2){mnA, mnB} * (f32x2){rA, rB};                    \
        const f32x2 ssv = tt * tt;                                               \
        f32x2 po = fma2(ssv, splat2(-0.03357890f), splat2(0.15084052f));         \
        po = fma2(ssv, po, splat2(-0.33355581f));                                \
        po = fma2(ssv, po, splat2(0.55446223f));                                 \
        po = fma2(ssv, po, splat2(-0.95289958f));                                \
        po = fma2(ssv, po, splat2(2.86472384f));   /* pre-scaled by 9/pi */      \
        const f32x2 w   = tt * po;                                               \
        const f32x2 w45 = splat2(4.5f) - w;                                      \
        const float vA = (faA > fbA) ? w45.x : w.x;                              \
        const float vB = (faB > fbB) ? w45.y : w.y;                              \
        const f32x2 vv = (f32x2){vA, vB};                                        \
        const f32x2 v9 = splat2(9.0f) - vv;                                      \
        const int sxA = (int)(__float_as_uint(gx.x) ^ __float_as_uint(gy.x));    \
        const int sxB = (int)(__float_as_uint(gx.y) ^ __float_as_uint(gy.y));    \
        const float upA = (sxA < 0) ? v9.x : vA;                                 \
        const float upB = (sxB < 0) ? v9.y : vB;                                 \
        const f32x2 up2 = (f32x2){upA, upB};                                     \
        const f32x2 rn2 = (f32x2){__builtin_rintf(upA), __builtin_rintf(upB)};   \
        const f32x2 d2  = up2 - rn2;                                             \
        if (fabsf(d2.x) > 1.2e-4f) {            /* NaN -> false -> slow */       \
            LA = (int)upA; W0A = nA; W1A = 1.0f - nA;                            \
        } else {                                                                 \
            const float ph  = (float)atan2((double)gx.x, (double)gy.x);          \
            const float pbf = ph / (float)M_PI * 9.0f;                           \
            int lo = (int)floorf(pbf) % NB; if (lo < 0) lo += NB;                \
            int hi = (int)ceilf(pbf)  % NB; if (hi < 0) hi += NB;                \
            LA = lo;                                                             \
            if (lo == hi) { W0A = nA + (1.0f - nA); W1A = 0.0f; }                \
            else          { W0A = nA; W1A = 1.0f - nA; }                         \
        }                                                                        \
        if (fabsf(d2.y) > 1.2e-4f) {                                             \
            LB = (int)upB; W0B = nB; W1B = 1.0f - nB;                            \
        } else {                                                                 \
            const float ph  = (float)atan2((double)gx.y, (double)gy.y);          \
            const float pbf = ph / (float)M_PI * 9.0f;                           \
            int lo = (int)floorf(pbf) % NB; if (lo < 0) lo += NB;                \
            int hi = (int)ceilf(pbf)  % NB; if (hi < 0) hi += NB;                \
            LB = lo;                                                             \
            if (lo == hi) { W0B = nB + (1.0f - nB); W1B = 0.0f; }                \
            else          { W0B = nB; W1B = 1.0f - nB; }                         \
        }                                                                        \
    }

    f32x2 bins2[NB];
#pragma unroll
    for (int b = 0; b < NB; b++) bins2[b] = splat2(0.0f);

    // packed rolling windows over this thread's 8 rows (LDS rows rbase..rbase+9):
    // .x = chain A (rows rbase..rbase+3+2), .y = chain B (rows rbase+4..)
    f32x2 wa[3], wb[3], wc[3];
    {
        const float* p0 = &sgray[(rbase + 0) * LSTR + c];
        const float* p1 = &sgray[(rbase + 1) * LSTR + c];
        const float* p4 = &sgray[(rbase + 4) * LSTR + c];
        const float* p5 = &sgray[(rbase + 5) * LSTR + c];
#pragma unroll
        for (int i = 0; i < 3; i++) {
            wa[i] = (f32x2){p0[3 + i], p4[3 + i]};
            wb[i] = (f32x2){p1[3 + i], p5[3 + i]};
        }
    }

#pragma unroll
    for (int k = 0; k < 4; k++) {
        const float* pA = &sgray[(rbase + k + 2) * LSTR + c];
        const float* pB = &sgray[(rbase + k + 6) * LSTR + c];
#pragma unroll
        for (int i = 0; i < 3; i++) wc[i] = (f32x2){pA[3 + i], pB[3 + i]};

        int LA, LB; float W0A, W1A, W0B, W1B;
        PIXEL2(wa, wb, wc, LA, LB, W0A, W1A, W0B, W1B)

        const f32x2 w0 = (f32x2){W0A, W0B};
        const f32x2 w1 = (f32x2){W1A, W1B};
        f32x2 sel[NB];
#pragma unroll
        for (int b = 0; b < NB; b++)
            sel[b] = (f32x2){(LA == b) ? 1.0f : 0.0f, (LB == b) ? 1.0f : 0.0f};
#pragma unroll
        for (int b = 0; b < NB; b++)
            bins2[b] = fma2(sel[b], w0, bins2[b]);           // v_pk_fma_f32
#pragma unroll
        for (int b = 0; b < NB; b++)
            bins2[b] = fma2(sel[(b + 8) % 9], w1, bins2[b]); // W1 at L+1 mod 9

#pragma unroll
        for (int q = 0; q < 3; q++) { wa[q] = wb[q]; wb[q] = wc[q]; }
    }
#undef PIXEL2

    float* mybins = &sbins[t * NB];
#pragma unroll
    for (int b = 0; b < NB; b++) mybins[b] = bins2[b].x + bins2[b].y;
    __syncthreads();

    // cells: (rh, cc) with cc 0..15; cell gathers threads rh*128+8cc..+7.
    // 288 outputs; fixed-order sum of 8.
    for (int idx = t; idx < NB * 32; idx += 256) {
        const int b   = idx >> 5;
        const int cel = idx & 31;
        const int crh = cel >> 4;
        const int cc  = cel & 15;
        const int base = (crh * 128 + 8 * cc) * NB + b;
        float s = sbins[base];
#pragma unroll
        for (int j = 1; j < 8; j++) s += sbins[base + j * NB];
        out[((size_t)n * NB + b) * 4096 + (size_t)(band * 2 + crh) * 64
            + grp * 16 + cc] = s * (1.0f / 64.0f);
    }
}

extern "C" void kernel_launch(void* const* d_in, const int* in_sizes, int n_in,
                              void* d_out, int out_size, void* d_ws, size_t ws_size,
                              hipStream_t stream) {
    const float* x = (const float*)d_in[0];
    float* out = (float*)d_out;
    // 32 images x 32 bands x 4 col-groups = 4096 blocks of 256
    hog_kernel<<<4096, 256, 0, stream>>>(x, out);
}